// Round 11
// baseline (660.641 us; speedup 1.0000x reference)
//
#include <hip/hip_runtime.h>
#include <hip/hip_fp16.h>
#include <hip/hip_cooperative_groups.h>
#include <cstdint>
#include <cstddef>

namespace cg = cooperative_groups;

#define NN 100000
#define NE 1600000
#define D 128
#define NBK 782            // ceil(NN / 128) buckets of 128 nodes
#define NCHK 256           // edge chunks == cooperative grid size
#define ECH 6250           // edges per chunk (256*6250 = 1.6M exact)

typedef _Float16 half8 __attribute__((ext_vector_type(8)));
typedef _Float16 half4v __attribute__((ext_vector_type(4)));
typedef float f32x4 __attribute__((ext_vector_type(4)));

// ---------------- workspace layout (bytes) ----------------
// part  : NE u32      @ 0          (6,400,000)   } dead after csr_k; overlapped by h
// offs  : 256*782 u32 @ 6,400,000  (  800,768)   }
// base  : 783 u32     @ 7,300,000  (    3,132)   }
// h'    : NN*128 f16  @ 0          (25,600,000)  = dinv[row] * (x@W1), written after CSR
// z'    : NN*2 f32    @ 25,600,000 (   800,000)
// dinv  : NN f32      @ 26,400,000 (   400,000)
// rp    : NN+1 u32    @ 26,800,000 (   400,004)
// col   : NE u32      @ 27,200,016 ( 6,400,000)
// Wt    : 128*128 f16 @ 33,600,016 (    32,768)  -> total 33,632,784

// Entire CSR build as ONE cooperative kernel: hist -> chunk-scan -> bucket-scan
// -> scatter -> per-bucket finalize. 256 blocks x 1024 thr (16 waves/CU, all
// co-resident). Saves 4 launch gaps + low-occupancy phases of the 5-kernel chain.
__launch_bounds__(1024)
__global__ void csr_k(const int* __restrict__ ei,
                      unsigned* __restrict__ offs, unsigned* __restrict__ base,
                      unsigned* __restrict__ part,
                      unsigned* __restrict__ rp, float* __restrict__ dinv,
                      unsigned* __restrict__ col,
                      const float* __restrict__ W, _Float16* __restrict__ Wt) {
    cg::grid_group grid = cg::this_grid();
    __shared__ unsigned smem[1024];
    int tid = threadIdx.x, b = blockIdx.x;

    // ---- Phase A: per-chunk LDS histogram over dst buckets (+ fused Wt build)
    for (int k = tid; k < NBK; k += 1024) smem[k] = 0u;
    __syncthreads();
    {
        int e0 = b * ECH;
        for (int i = tid; i < ECH; i += 1024) {
            int d = ei[NE + e0 + i];
            atomicAdd(&smem[d >> 7], 1u);
        }
    }
    if (b < 16) {  // Wt[n][k] = fp16 W[k][n], 16384 elems over 16 blocks
        int idx = b * 1024 + tid;
        int n = idx >> 7, k = idx & 127;
        Wt[idx] = (_Float16)W[k * 128 + n];
    }
    __syncthreads();
    for (int k = tid; k < NBK; k += 1024) offs[(size_t)b * NBK + k] = smem[k];
    __threadfence();
    grid.sync();

    // ---- Phase B: per-bucket exclusive scan over the 256 chunks (4 buckets/block)
    {
        int g = tid >> 8, t8 = tid & 255;
        int k = b + (g << 8);
        unsigned v = (k < NBK) ? offs[(size_t)t8 * NBK + k] : 0u;
        unsigned* sh = &smem[g << 8];
        sh[t8] = v;
        __syncthreads();
        for (int off = 1; off < 256; off <<= 1) {
            unsigned u = (t8 >= off) ? sh[t8 - off] : 0u;
            __syncthreads();
            sh[t8] += u;
            __syncthreads();
        }
        if (k < NBK) {
            offs[(size_t)t8 * NBK + k] = sh[t8] - v;  // exclusive over chunks
            if (t8 == 255) base[k] = sh[255];          // bucket total
        }
    }
    __threadfence();
    grid.sync();

    // ---- Phase C: exclusive scan of bucket totals (block 0 only)
    if (b == 0) {
        unsigned v = (tid < NBK) ? base[tid] : 0u;
        smem[tid] = v;
        __syncthreads();
        for (int off = 1; off < 1024; off <<= 1) {
            unsigned u = (tid >= off) ? smem[tid - off] : 0u;
            __syncthreads();
            smem[tid] += u;
            __syncthreads();
        }
        if (tid < NBK) base[tid] = smem[tid] - v;
        if (tid == NBK) base[NBK] = smem[NBK - 1];
        if (tid == 0) rp[NN] = NE;
        __threadfence();
    }
    grid.sync();

    // ---- Phase D: scatter packed edges into bucket-partitioned part[]
    for (int k = tid; k < NBK; k += 1024) smem[k] = base[k] + offs[(size_t)b * NBK + k];
    __syncthreads();
    {
        int e0 = b * ECH;
        for (int i = tid; i < ECH; i += 1024) {
            int s = ei[e0 + i];
            int d = ei[NE + e0 + i];
            unsigned pos = atomicAdd(&smem[d >> 7], 1u);
            part[pos] = (unsigned)s | ((unsigned)(d & 127) << 20);
        }
    }
    __threadfence();
    grid.sync();

    // ---- Phase E: per-bucket finalize (count, scan, rp/dinv, regroup col)
    unsigned* c = smem; unsigned* pp = smem + 128; unsigned* run = smem + 256;
    for (int kk = b; kk < NBK; kk += NCHK) {
        int n0 = kk << 7;
        int nodes = (NN - n0 < 128) ? (NN - n0) : 128;
        unsigned e0 = base[kk], e1 = base[kk + 1];

        if (tid < 128) c[tid] = 0u;
        __syncthreads();
        for (unsigned e = e0 + tid; e < e1; e += 1024)
            atomicAdd(&c[(part[e] >> 20) & 127], 1u);
        __syncthreads();

        unsigned myc = (tid < 128) ? c[tid] : 0u;
        if (tid < 128) pp[tid] = myc;
        __syncthreads();
        for (int off = 1; off < 128; off <<= 1) {
            unsigned u = 0;
            if (tid < 128 && tid >= off) u = pp[tid - off];
            __syncthreads();
            if (tid < 128) pp[tid] += u;
            __syncthreads();
        }
        if (tid < 128) {
            unsigned excl = pp[tid] - myc;
            run[tid] = excl;
            if (tid < nodes) {
                rp[n0 + tid] = e0 + excl;
                dinv[n0 + tid] = rsqrtf((float)(myc + 1u));
            }
        }
        __syncthreads();
        for (unsigned e = e0 + tid; e < e1; e += 1024) {
            unsigned v = part[e];
            unsigned dlo = (v >> 20) & 127;
            unsigned pos = e0 + atomicAdd(&run[dlo], 1u);
            col[pos] = v & 0xFFFFFu;
        }
        __syncthreads();  // c/pp/run reused next iteration
    }
}

// h' = dinv ⊙ (x @ W1), fp16 out, MFMA 16x16x32 f16. 128 rows/block, 4 waves;
// wave w covers rows w*32..w*32+31 (2 row-tiles) × all 8 col-tiles.
// Verified layouts: A[m=lane&15][k=(lane>>4)*8+j], B[k][n=lane&15],
//                   C/D col=lane&15 row=(lane>>4)*4+reg.
__launch_bounds__(256)
__global__ void gemm1_k(const float* __restrict__ x, const _Float16* __restrict__ Wt,
                        const float* __restrict__ dinv, _Float16* __restrict__ h) {
    __shared__ _Float16 wt[128 * 136];  // B: wt[n][k]; reused as epilogue buffer
    __shared__ _Float16 xs[128 * 72];   // A: xs[row][k within 64-half]
    int tid = threadIdx.x;
    int rb = blockIdx.x * 128;
    int w = tid >> 6, lane = tid & 63;
    int m = lane & 15, q4 = lane >> 4;

#pragma unroll
    for (int q = 0; q < 8; q++) {
        int idx = q * 256 + tid;
        int n = idx >> 4, k8 = (idx & 15) * 8;
        *(half8*)(&wt[n * 136 + k8]) = *(const half8*)(Wt + n * 128 + k8);
    }

    f32x4 acc[2][8];
#pragma unroll
    for (int rt = 0; rt < 2; rt++)
#pragma unroll
        for (int nt = 0; nt < 8; nt++) acc[rt][nt] = (f32x4){0.f, 0.f, 0.f, 0.f};

    for (int ks = 0; ks <= 64; ks += 64) {
        if (ks) __syncthreads();
#pragma unroll
        for (int q = 0; q < 8; q++) {
            int idx = q * 256 + tid;
            int row = idx >> 4;
            int c4 = (idx & 15) * 4;
            int gr = rb + row;
            float4 v = (gr < NN) ? *(const float4*)(x + (size_t)gr * 128 + ks + c4)
                                 : make_float4(0, 0, 0, 0);
            half4v hv = { (_Float16)v.x, (_Float16)v.y, (_Float16)v.z, (_Float16)v.w };
            *(half4v*)(&xs[row * 72 + c4]) = hv;
        }
        __syncthreads();

#pragma unroll
        for (int kc = 0; kc < 2; kc++) {
            half8 a0 = *(const half8*)(&xs[(w * 32 + m) * 72 + kc * 32 + q4 * 8]);
            half8 a1 = *(const half8*)(&xs[(w * 32 + 16 + m) * 72 + kc * 32 + q4 * 8]);
#pragma unroll
            for (int nt = 0; nt < 8; nt++) {
                half8 bf = *(const half8*)(&wt[(nt * 16 + m) * 136 + ks + kc * 32 + q4 * 8]);
                acc[0][nt] = __builtin_amdgcn_mfma_f32_16x16x32_f16(a0, bf, acc[0][nt], 0, 0, 0);
                acc[1][nt] = __builtin_amdgcn_mfma_f32_16x16x32_f16(a1, bf, acc[1][nt], 0, 0, 0);
            }
        }
    }

    float dv[2][4];
#pragma unroll
    for (int rt = 0; rt < 2; rt++)
#pragma unroll
        for (int r = 0; r < 4; r++) {
            int ri = rb + w * 32 + rt * 16 + q4 * 4 + r;
            dv[rt][r] = (ri < NN) ? dinv[ri] : 0.f;
        }
    __syncthreads();
#pragma unroll
    for (int rt = 0; rt < 2; rt++)
#pragma unroll
        for (int nt = 0; nt < 8; nt++)
#pragma unroll
            for (int r = 0; r < 4; r++)
                wt[(w * 32 + rt * 16 + q4 * 4 + r) * 136 + nt * 16 + m] =
                    (_Float16)(acc[rt][nt][r] * dv[rt][r]);
    __syncthreads();
#pragma unroll
    for (int q = 0; q < 8; q++) {
        int idx = q * 256 + tid;
        int row = idx >> 4;
        int c8 = (idx & 15) * 8;
        int gr = rb + row;
        if (gr < NN)
            *(half8*)(h + (size_t)gr * 128 + c8) = *(const half8*)(&wt[row * 136 + c8]);
    }
}

#define GATHER(sv, vv) \
    { unsigned s_ = __builtin_amdgcn_readfirstlane(col[sv]); \
      vv = __half22float2(hb[(size_t)(s_ * 64u + lane)]); }

// Layer-1 aggregation of prescaled h' + bias/ReLU + 128x2 W2 projection.
__launch_bounds__(256)
__global__ void agg1_k(const _Float16* __restrict__ h, const unsigned* __restrict__ rp,
                       const unsigned* __restrict__ col, const float* __restrict__ dinv,
                       const float* __restrict__ b1, const float* __restrict__ W2,
                       float* __restrict__ z) {
    int i = (blockIdx.x * 256 + threadIdx.x) >> 6;
    int lane = threadIdx.x & 63;
    if (i >= NN) return;

    const __half2* hb = (const __half2*)h;
    float di = dinv[i];
    float2 hv = __half22float2(hb[(size_t)i * 64 + lane]);
    float ax = hv.x, ay = hv.y;  // self term h'[i]

    unsigned p0 = __builtin_amdgcn_readfirstlane(rp[i]);
    unsigned p1 = __builtin_amdgcn_readfirstlane(rp[i + 1]);
    unsigned e = p0;
    for (; e + 16 <= p1; e += 16) {
        float2 v0, v1, v2, v3, v4, v5, v6, v7, v8, v9, va, vb, vc, vd, ve, vf;
        GATHER(e, v0)      GATHER(e + 1, v1)  GATHER(e + 2, v2)  GATHER(e + 3, v3)
        GATHER(e + 4, v4)  GATHER(e + 5, v5)  GATHER(e + 6, v6)  GATHER(e + 7, v7)
        GATHER(e + 8, v8)  GATHER(e + 9, v9)  GATHER(e + 10, va) GATHER(e + 11, vb)
        GATHER(e + 12, vc) GATHER(e + 13, vd) GATHER(e + 14, ve) GATHER(e + 15, vf)
        ax += ((v0.x + v1.x) + (v2.x + v3.x)) + ((v4.x + v5.x) + (v6.x + v7.x))
            + ((v8.x + v9.x) + (va.x + vb.x)) + ((vc.x + vd.x) + (ve.x + vf.x));
        ay += ((v0.y + v1.y) + (v2.y + v3.y)) + ((v4.y + v5.y) + (v6.y + v7.y))
            + ((v8.y + v9.y) + (va.y + vb.y)) + ((vc.y + vd.y) + (ve.y + vf.y));
    }
    for (; e + 4 <= p1; e += 4) {
        float2 v0, v1, v2, v3;
        GATHER(e, v0) GATHER(e + 1, v1) GATHER(e + 2, v2) GATHER(e + 3, v3)
        ax += (v0.x + v1.x) + (v2.x + v3.x);
        ay += (v0.y + v1.y) + (v2.y + v3.y);
    }
    for (; e < p1; ++e) {
        float2 v;
        GATHER(e, v)
        ax += v.x;
        ay += v.y;
    }
    ax *= di;
    ay *= di;

    float2 bv = ((const float2*)b1)[lane];
    float h0 = fmaxf(ax + bv.x, 0.f);
    float h1 = fmaxf(ay + bv.y, 0.f);

    float4 w = ((const float4*)W2)[lane];
    float pz0 = fmaf(h0, w.x, h1 * w.z);
    float pz1 = fmaf(h0, w.y, h1 * w.w);
#pragma unroll
    for (int off = 32; off > 0; off >>= 1) {
        pz0 += __shfl_down(pz0, off);
        pz1 += __shfl_down(pz1, off);
    }
    if (lane == 0) {
        float2* zp = (float2*)(z + (size_t)i * 2);
        *zp = make_float2(pz0 * di, pz1 * di);  // prescale for layer-2 aggregation
    }
}

// Layer-2 aggregation over prescaled z'. 16 lanes per node.
__launch_bounds__(256)
__global__ void agg2_k(const float* __restrict__ z, const unsigned* __restrict__ rp,
                       const unsigned* __restrict__ col, const float* __restrict__ dinv,
                       const float* __restrict__ b2, float* __restrict__ out) {
    int i = (blockIdx.x * 256 + threadIdx.x) >> 4;
    int sl = threadIdx.x & 15;
    if (i >= NN) return;

    unsigned p0 = rp[i], p1 = rp[i + 1];
    float a0 = 0.f, a1 = 0.f;
    for (unsigned e = p0 + sl; e < p1; e += 16) {
        unsigned s = col[e];
        float2 v = ((const float2*)z)[s];
        a0 += v.x;
        a1 += v.y;
    }
#pragma unroll
    for (int off = 8; off > 0; off >>= 1) {
        a0 += __shfl_down(a0, off, 16);
        a1 += __shfl_down(a1, off, 16);
    }
    if (sl == 0) {
        float di = dinv[i];
        float2 zi = ((const float2*)z)[i];
        out[(size_t)i * 2]     = (a0 + zi.x) * di + b2[0];
        out[(size_t)i * 2 + 1] = (a1 + zi.y) * di + b2[1];
    }
}

extern "C" void kernel_launch(void* const* d_in, const int* in_sizes, int n_in,
                              void* d_out, int out_size, void* d_ws, size_t ws_size,
                              hipStream_t stream) {
    const float* x  = (const float*)d_in[0];
    const int*   ei = (const int*)d_in[1];
    const float* W1 = (const float*)d_in[2];
    const float* b1 = (const float*)d_in[3];
    const float* W2 = (const float*)d_in[4];
    const float* b2 = (const float*)d_in[5];
    float* out = (float*)d_out;

    char* ws = (char*)d_ws;
    unsigned* part = (unsigned*)(ws);               // overlaps h, dead before gemm1
    unsigned* offs = (unsigned*)(ws + 6400000);     // overlaps h
    unsigned* base = (unsigned*)(ws + 7300000);     // overlaps h
    _Float16* h    = (_Float16*)(ws);
    float*    z    = (float*)(ws + 25600000);
    float*    dinv = (float*)(ws + 26400000);
    unsigned* rp   = (unsigned*)(ws + 26800000);
    unsigned* col  = (unsigned*)(ws + 27200016);
    _Float16* Wt   = (_Float16*)(ws + 33600016);

    void* args[] = { (void*)&ei, (void*)&offs, (void*)&base, (void*)&part,
                     (void*)&rp, (void*)&dinv, (void*)&col, (void*)&W1, (void*)&Wt };
    hipLaunchCooperativeKernel((void*)csr_k, dim3(NCHK), dim3(1024), args, 0, stream);

    gemm1_k<<<(NN + 127) / 128, 256, 0, stream>>>(x, Wt, dinv, h);
    agg1_k<<<(NN + 3) / 4, 256, 0, stream>>>(h, rp, col, dinv, b1, W2, z);
    agg2_k<<<(NN * 16 + 255) / 256, 256, 0, stream>>>(z, rp, col, dinv, b2, out);
}

// Round 12
// 584.961 us; speedup vs baseline: 1.1294x; 1.1294x over previous
//
#include <hip/hip_runtime.h>
#include <hip/hip_fp16.h>
#include <cstdint>
#include <cstddef>

#define NN 100000
#define NE 1600000
#define D 128
#define NBK 782            // ceil(NN / 128) buckets of 128 nodes
#define CAP 2560           // padded bucket capacity (mean 2046, sigma 45 -> +11 sigma)

typedef _Float16 half8 __attribute__((ext_vector_type(8)));
typedef _Float16 half4v __attribute__((ext_vector_type(4)));
typedef float f32x4 __attribute__((ext_vector_type(4)));

// ---------------- workspace layout (bytes) ----------------
// part  : 782*2560 u32 @ 0          (8,007,680)  } dead after fin_k; overlapped by h
// gcnt  : 782 u32      @ 8,100,000  (    3,128)  }
// base  : 783 u32      @ 8,110,000  (    3,132)  }
// h'    : NN*128 f16   @ 0          (25,600,000) = dinv[row] * (x@W1), written after CSR
// z'    : NN*2 f32     @ 25,600,000 (   800,000)
// dinv  : NN f32       @ 26,400,000 (   400,000)
// rp    : NN+1 u32     @ 26,800,000 (   400,004)
// col   : NE u32       @ 27,200,016 ( 6,400,000)
// Wt    : 128*128 f16  @ 33,600,016 (    32,768) -> total 33,632,784

// Scatter edges directly into padded per-bucket regions via global atomics on
// 782 L2-hot counters (no histogram pass, no chunk scan). Blocks 0..63 also
// emit Wt[n][k] = fp16 W1[k][n].
__launch_bounds__(256)
__global__ void scatter_k(const int* __restrict__ ei, unsigned* __restrict__ gcnt,
                          unsigned* __restrict__ part,
                          const float* __restrict__ W, _Float16* __restrict__ Wt) {
    int i = (blockIdx.x * 256 + threadIdx.x) * 4;
    if (blockIdx.x < 64) {
        int idx = blockIdx.x * 256 + threadIdx.x;
        int n = idx >> 7, k = idx & 127;
        Wt[idx] = (_Float16)W[k * 128 + n];
    }
    if (i >= NE) return;
    int4 s4 = *(const int4*)(ei + i);
    int4 d4 = *(const int4*)(ei + NE + i);
    unsigned b, p;
    b = (unsigned)d4.x >> 7; p = atomicAdd(&gcnt[b], 1u);
    part[b * CAP + p] = (unsigned)s4.x | ((unsigned)(d4.x & 127) << 20);
    b = (unsigned)d4.y >> 7; p = atomicAdd(&gcnt[b], 1u);
    part[b * CAP + p] = (unsigned)s4.y | ((unsigned)(d4.y & 127) << 20);
    b = (unsigned)d4.z >> 7; p = atomicAdd(&gcnt[b], 1u);
    part[b * CAP + p] = (unsigned)s4.z | ((unsigned)(d4.z & 127) << 20);
    b = (unsigned)d4.w >> 7; p = atomicAdd(&gcnt[b], 1u);
    part[b * CAP + p] = (unsigned)s4.w | ((unsigned)(d4.w & 127) << 20);
}

// Exclusive scan of bucket totals; base[NBK] = NE; rp[NN] = NE.
__global__ void scan_k(const unsigned* __restrict__ gcnt, unsigned* __restrict__ base,
                       unsigned* __restrict__ rp) {
    __shared__ unsigned sh[1024];
    int t = threadIdx.x;
    unsigned v = (t < NBK) ? gcnt[t] : 0u;
    sh[t] = v;
    __syncthreads();
    for (int off = 1; off < 1024; off <<= 1) {
        unsigned u = (t >= off) ? sh[t - off] : 0u;
        __syncthreads();
        sh[t] += u;
        __syncthreads();
    }
    if (t < NBK) base[t] = sh[t] - v;
    if (t == NBK) base[NBK] = sh[NBK - 1];
    if (t == 0) rp[NN] = NE;
}

// One block per bucket: count per node in LDS, scan, emit rp/dinv, regroup col
// (contiguous, from the padded part slice).
__launch_bounds__(256)
__global__ void fin_k(const unsigned* __restrict__ part, const unsigned* __restrict__ gcnt,
                      const unsigned* __restrict__ base,
                      unsigned* __restrict__ rp, float* __restrict__ dinv,
                      unsigned* __restrict__ col) {
    __shared__ unsigned c[128], p[128], run[128];
    int tid = threadIdx.x, k = blockIdx.x;
    int n0 = k << 7;
    int nodes = (NN - n0 < 128) ? (NN - n0) : 128;
    unsigned cnt = gcnt[k];
    unsigned e0 = base[k];
    const unsigned* src = part + (size_t)k * CAP;

    if (tid < 128) c[tid] = 0u;
    __syncthreads();
    for (unsigned e = tid; e < cnt; e += 256)
        atomicAdd(&c[(src[e] >> 20) & 127], 1u);
    __syncthreads();

    unsigned myc = (tid < 128) ? c[tid] : 0u;
    if (tid < 128) p[tid] = myc;
    __syncthreads();
    for (int off = 1; off < 128; off <<= 1) {
        unsigned u = 0;
        if (tid < 128 && tid >= off) u = p[tid - off];
        __syncthreads();
        if (tid < 128) p[tid] += u;
        __syncthreads();
    }
    if (tid < 128) {
        unsigned excl = p[tid] - myc;
        run[tid] = excl;
        if (tid < nodes) {
            rp[n0 + tid] = e0 + excl;
            dinv[n0 + tid] = rsqrtf((float)(myc + 1u));
        }
    }
    __syncthreads();

    for (unsigned e = tid; e < cnt; e += 256) {
        unsigned v = src[e];
        unsigned dlo = (v >> 20) & 127;
        unsigned pos = e0 + atomicAdd(&run[dlo], 1u);
        col[pos] = v & 0xFFFFFu;
    }
}

// h' = dinv ⊙ (x @ W1), fp16 out, MFMA 16x16x32 f16. 128 rows/block, 4 waves;
// wave w covers rows w*32..w*32+31 (2 row-tiles) × all 8 col-tiles.
// Verified layouts: A[m=lane&15][k=(lane>>4)*8+j], B[k][n=lane&15],
//                   C/D col=lane&15 row=(lane>>4)*4+reg.
__launch_bounds__(256)
__global__ void gemm1_k(const float* __restrict__ x, const _Float16* __restrict__ Wt,
                        const float* __restrict__ dinv, _Float16* __restrict__ h) {
    __shared__ _Float16 wt[128 * 136];  // B: wt[n][k]; reused as epilogue buffer
    __shared__ _Float16 xs[128 * 72];   // A: xs[row][k within 64-half]
    int tid = threadIdx.x;
    int rb = blockIdx.x * 128;
    int w = tid >> 6, lane = tid & 63;
    int m = lane & 15, q4 = lane >> 4;

#pragma unroll
    for (int q = 0; q < 8; q++) {
        int idx = q * 256 + tid;
        int n = idx >> 4, k8 = (idx & 15) * 8;
        *(half8*)(&wt[n * 136 + k8]) = *(const half8*)(Wt + n * 128 + k8);
    }

    f32x4 acc[2][8];
#pragma unroll
    for (int rt = 0; rt < 2; rt++)
#pragma unroll
        for (int nt = 0; nt < 8; nt++) acc[rt][nt] = (f32x4){0.f, 0.f, 0.f, 0.f};

    for (int ks = 0; ks <= 64; ks += 64) {
        if (ks) __syncthreads();
#pragma unroll
        for (int q = 0; q < 8; q++) {
            int idx = q * 256 + tid;
            int row = idx >> 4;
            int c4 = (idx & 15) * 4;
            int gr = rb + row;
            float4 v = (gr < NN) ? *(const float4*)(x + (size_t)gr * 128 + ks + c4)
                                 : make_float4(0, 0, 0, 0);
            half4v hv = { (_Float16)v.x, (_Float16)v.y, (_Float16)v.z, (_Float16)v.w };
            *(half4v*)(&xs[row * 72 + c4]) = hv;
        }
        __syncthreads();

#pragma unroll
        for (int kc = 0; kc < 2; kc++) {
            half8 a0 = *(const half8*)(&xs[(w * 32 + m) * 72 + kc * 32 + q4 * 8]);
            half8 a1 = *(const half8*)(&xs[(w * 32 + 16 + m) * 72 + kc * 32 + q4 * 8]);
#pragma unroll
            for (int nt = 0; nt < 8; nt++) {
                half8 bf = *(const half8*)(&wt[(nt * 16 + m) * 136 + ks + kc * 32 + q4 * 8]);
                acc[0][nt] = __builtin_amdgcn_mfma_f32_16x16x32_f16(a0, bf, acc[0][nt], 0, 0, 0);
                acc[1][nt] = __builtin_amdgcn_mfma_f32_16x16x32_f16(a1, bf, acc[1][nt], 0, 0, 0);
            }
        }
    }

    float dv[2][4];
#pragma unroll
    for (int rt = 0; rt < 2; rt++)
#pragma unroll
        for (int r = 0; r < 4; r++) {
            int ri = rb + w * 32 + rt * 16 + q4 * 4 + r;
            dv[rt][r] = (ri < NN) ? dinv[ri] : 0.f;
        }
    __syncthreads();
#pragma unroll
    for (int rt = 0; rt < 2; rt++)
#pragma unroll
        for (int nt = 0; nt < 8; nt++)
#pragma unroll
            for (int r = 0; r < 4; r++)
                wt[(w * 32 + rt * 16 + q4 * 4 + r) * 136 + nt * 16 + m] =
                    (_Float16)(acc[rt][nt][r] * dv[rt][r]);
    __syncthreads();
#pragma unroll
    for (int q = 0; q < 8; q++) {
        int idx = q * 256 + tid;
        int row = idx >> 4;
        int c8 = (idx & 15) * 8;
        int gr = rb + row;
        if (gr < NN)
            *(half8*)(h + (size_t)gr * 128 + c8) = *(const half8*)(&wt[row * 136 + c8]);
    }
}

#define GATHER(sv, vv) \
    { unsigned s_ = __builtin_amdgcn_readfirstlane(col[sv]); \
      vv = __half22float2(hb[(size_t)(s_ * 64u + lane)]); }

// Layer-1 aggregation of prescaled h' + bias/ReLU + 128x2 W2 projection.
__launch_bounds__(256)
__global__ void agg1_k(const _Float16* __restrict__ h, const unsigned* __restrict__ rp,
                       const unsigned* __restrict__ col, const float* __restrict__ dinv,
                       const float* __restrict__ b1, const float* __restrict__ W2,
                       float* __restrict__ z) {
    int i = (blockIdx.x * 256 + threadIdx.x) >> 6;
    int lane = threadIdx.x & 63;
    if (i >= NN) return;

    const __half2* hb = (const __half2*)h;
    float di = dinv[i];
    float2 hv = __half22float2(hb[(size_t)i * 64 + lane]);
    float ax = hv.x, ay = hv.y;  // self term h'[i]

    unsigned p0 = __builtin_amdgcn_readfirstlane(rp[i]);
    unsigned p1 = __builtin_amdgcn_readfirstlane(rp[i + 1]);
    unsigned e = p0;
    for (; e + 16 <= p1; e += 16) {
        float2 v0, v1, v2, v3, v4, v5, v6, v7, v8, v9, va, vb, vc, vd, ve, vf;
        GATHER(e, v0)      GATHER(e + 1, v1)  GATHER(e + 2, v2)  GATHER(e + 3, v3)
        GATHER(e + 4, v4)  GATHER(e + 5, v5)  GATHER(e + 6, v6)  GATHER(e + 7, v7)
        GATHER(e + 8, v8)  GATHER(e + 9, v9)  GATHER(e + 10, va) GATHER(e + 11, vb)
        GATHER(e + 12, vc) GATHER(e + 13, vd) GATHER(e + 14, ve) GATHER(e + 15, vf)
        ax += ((v0.x + v1.x) + (v2.x + v3.x)) + ((v4.x + v5.x) + (v6.x + v7.x))
            + ((v8.x + v9.x) + (va.x + vb.x)) + ((vc.x + vd.x) + (ve.x + vf.x));
        ay += ((v0.y + v1.y) + (v2.y + v3.y)) + ((v4.y + v5.y) + (v6.y + v7.y))
            + ((v8.y + v9.y) + (va.y + vb.y)) + ((vc.y + vd.y) + (ve.y + vf.y));
    }
    for (; e + 4 <= p1; e += 4) {
        float2 v0, v1, v2, v3;
        GATHER(e, v0) GATHER(e + 1, v1) GATHER(e + 2, v2) GATHER(e + 3, v3)
        ax += (v0.x + v1.x) + (v2.x + v3.x);
        ay += (v0.y + v1.y) + (v2.y + v3.y);
    }
    for (; e < p1; ++e) {
        float2 v;
        GATHER(e, v)
        ax += v.x;
        ay += v.y;
    }
    ax *= di;
    ay *= di;

    float2 bv = ((const float2*)b1)[lane];
    float h0 = fmaxf(ax + bv.x, 0.f);
    float h1 = fmaxf(ay + bv.y, 0.f);

    float4 w = ((const float4*)W2)[lane];
    float pz0 = fmaf(h0, w.x, h1 * w.z);
    float pz1 = fmaf(h0, w.y, h1 * w.w);
#pragma unroll
    for (int off = 32; off > 0; off >>= 1) {
        pz0 += __shfl_down(pz0, off);
        pz1 += __shfl_down(pz1, off);
    }
    if (lane == 0) {
        float2* zp = (float2*)(z + (size_t)i * 2);
        *zp = make_float2(pz0 * di, pz1 * di);  // prescale for layer-2 aggregation
    }
}

// Layer-2 aggregation over prescaled z'. 16 lanes per node.
__launch_bounds__(256)
__global__ void agg2_k(const float* __restrict__ z, const unsigned* __restrict__ rp,
                       const unsigned* __restrict__ col, const float* __restrict__ dinv,
                       const float* __restrict__ b2, float* __restrict__ out) {
    int i = (blockIdx.x * 256 + threadIdx.x) >> 4;
    int sl = threadIdx.x & 15;
    if (i >= NN) return;

    unsigned p0 = rp[i], p1 = rp[i + 1];
    float a0 = 0.f, a1 = 0.f;
    for (unsigned e = p0 + sl; e < p1; e += 16) {
        unsigned s = col[e];
        float2 v = ((const float2*)z)[s];
        a0 += v.x;
        a1 += v.y;
    }
#pragma unroll
    for (int off = 8; off > 0; off >>= 1) {
        a0 += __shfl_down(a0, off, 16);
        a1 += __shfl_down(a1, off, 16);
    }
    if (sl == 0) {
        float di = dinv[i];
        float2 zi = ((const float2*)z)[i];
        out[(size_t)i * 2]     = (a0 + zi.x) * di + b2[0];
        out[(size_t)i * 2 + 1] = (a1 + zi.y) * di + b2[1];
    }
}

extern "C" void kernel_launch(void* const* d_in, const int* in_sizes, int n_in,
                              void* d_out, int out_size, void* d_ws, size_t ws_size,
                              hipStream_t stream) {
    const float* x  = (const float*)d_in[0];
    const int*   ei = (const int*)d_in[1];
    const float* W1 = (const float*)d_in[2];
    const float* b1 = (const float*)d_in[3];
    const float* W2 = (const float*)d_in[4];
    const float* b2 = (const float*)d_in[5];
    float* out = (float*)d_out;

    char* ws = (char*)d_ws;
    unsigned* part = (unsigned*)(ws);               // overlaps h, dead before gemm1
    unsigned* gcnt = (unsigned*)(ws + 8100000);     // overlaps h
    unsigned* base = (unsigned*)(ws + 8110000);     // overlaps h
    _Float16* h    = (_Float16*)(ws);
    float*    z    = (float*)(ws + 25600000);
    float*    dinv = (float*)(ws + 26400000);
    unsigned* rp   = (unsigned*)(ws + 26800000);
    unsigned* col  = (unsigned*)(ws + 27200016);
    _Float16* Wt   = (_Float16*)(ws + 33600016);

    hipMemsetAsync(gcnt, 0, NBK * sizeof(unsigned), stream);
    scatter_k<<<(NE / 4 + 255) / 256, 256, 0, stream>>>(ei, gcnt, part, W1, Wt);
    scan_k<<<1, 1024, 0, stream>>>(gcnt, base, rp);
    fin_k<<<NBK, 256, 0, stream>>>(part, gcnt, base, rp, dinv, col);

    gemm1_k<<<(NN + 127) / 128, 256, 0, stream>>>(x, Wt, dinv, h);
    agg1_k<<<(NN + 3) / 4, 256, 0, stream>>>(h, rp, col, dinv, b1, W2, z);
    agg2_k<<<(NN * 16 + 255) / 256, 256, 0, stream>>>(z, rp, col, dinv, b2, out);
}

// Round 13
// 225.506 us; speedup vs baseline: 2.9296x; 2.5940x over previous
//
#include <hip/hip_runtime.h>
#include <hip/hip_fp16.h>
#include <cstdint>
#include <cstddef>

#define NN 100000
#define NE 1600000
#define D 128
#define NBK 782            // ceil(NN / 128) buckets of 128 nodes
#define NBLK_P 200         // partition chunks
#define EPB 8000           // edges per chunk (200*8000 = 1.6M exact)

typedef _Float16 half8 __attribute__((ext_vector_type(8)));
typedef _Float16 half4v __attribute__((ext_vector_type(4)));
typedef float f32x4 __attribute__((ext_vector_type(4)));

// ---------------- workspace layout (bytes) ----------------
// part  : NE u32      @ 0          (6,400,000)   } dead after p4_csr; overlapped by h
// offs  : 200*782 u32 @ 6,400,000  (  625,600)   }
// base  : 783 u32     @ 7,100,000  (    3,132)   }
// h'    : NN*128 f16  @ 0          (25,600,000)  = dinv[row] * (x@W1), written after CSR
// z'    : NN*2 f32    @ 25,600,000 (   800,000)
// dinv  : NN f32      @ 26,400,000 (   400,000)
// rp    : NN+1 u32    @ 26,800,000 (   400,004)
// col   : NE u32      @ 27,200,016 ( 6,400,000)
// Wt    : 128*128 f16 @ 33,600,016 (    32,768)  -> total 33,632,784

// P1: per-chunk LDS histogram over dst buckets. 1024 thr (was 256: 3 waves/CU
// was the bound). Blocks 0..15 also emit Wt[n][k] = fp16 W1[k][n].
__launch_bounds__(1024)
__global__ void p1_count_k(const int* __restrict__ ei, unsigned* __restrict__ offs,
                           const float* __restrict__ W, _Float16* __restrict__ Wt) {
    __shared__ unsigned hist[NBK];
    int tid = threadIdx.x, b = blockIdx.x;
    for (int k = tid; k < NBK; k += 1024) hist[k] = 0u;
    __syncthreads();
    int e0 = b * EPB;
    for (int i = tid * 4; i < EPB; i += 4096) {
        int4 d4 = *(const int4*)(ei + NE + e0 + i);
        atomicAdd(&hist[d4.x >> 7], 1u);
        atomicAdd(&hist[d4.y >> 7], 1u);
        atomicAdd(&hist[d4.z >> 7], 1u);
        atomicAdd(&hist[d4.w >> 7], 1u);
    }
    if (b < 16) {  // fused Wt transpose+cast (16384 elems over 16 blocks)
        int idx = b * 1024 + tid;
        int n = idx >> 7, k = idx & 127;
        Wt[idx] = (_Float16)W[k * 128 + n];
    }
    __syncthreads();
    for (int k = tid; k < NBK; k += 1024) offs[(size_t)b * NBK + k] = hist[k];
}

// P2a: block per bucket; parallel loads of the 200 per-chunk counts + LDS scan.
__launch_bounds__(256)
__global__ void p2a_k(unsigned* __restrict__ offs, unsigned* __restrict__ base) {
    __shared__ unsigned sh[256];
    int t = threadIdx.x, k = blockIdx.x;
    unsigned v = (t < NBLK_P) ? offs[(size_t)t * NBK + k] : 0u;
    sh[t] = v;
    __syncthreads();
    for (int off = 1; off < 256; off <<= 1) {
        unsigned u = (t >= off) ? sh[t - off] : 0u;
        __syncthreads();
        sh[t] += u;
        __syncthreads();
    }
    if (t < NBLK_P) offs[(size_t)t * NBK + k] = sh[t] - v;  // exclusive
    if (t == 255) base[k] = sh[255];                         // bucket total
}

// P2b: exclusive scan of bucket totals; base[NBK] = NE.
__global__ void p2b_k(unsigned* __restrict__ base) {
    __shared__ unsigned sh[1024];
    int t = threadIdx.x;
    unsigned v = (t < NBK) ? base[t] : 0u;
    sh[t] = v;
    __syncthreads();
    for (int off = 1; off < 1024; off <<= 1) {
        unsigned u = (t >= off) ? sh[t - off] : 0u;
        __syncthreads();
        sh[t] += u;
        __syncthreads();
    }
    if (t < NBK) base[t] = sh[t] - v;
    if (t == NBK) base[NBK] = sh[NBK - 1];
}

// P3: scatter packed edges into bucket-partitioned order via LDS running
// counters. 1024 thr for TLP; same 200 chunks (write-run lengths preserved).
__launch_bounds__(1024)
__global__ void p3_scatter_k(const int* __restrict__ ei, const unsigned* __restrict__ offs,
                             const unsigned* __restrict__ base, unsigned* __restrict__ part) {
    __shared__ unsigned lcnt[NBK];
    int tid = threadIdx.x, b = blockIdx.x;
    for (int k = tid; k < NBK; k += 1024) lcnt[k] = base[k] + offs[(size_t)b * NBK + k];
    __syncthreads();
    int e0 = b * EPB;
    for (int i = tid * 4; i < EPB; i += 4096) {
        int4 s4 = *(const int4*)(ei + e0 + i);
        int4 d4 = *(const int4*)(ei + NE + e0 + i);
        unsigned p;
        p = atomicAdd(&lcnt[d4.x >> 7], 1u); part[p] = (unsigned)s4.x | ((unsigned)(d4.x & 127) << 20);
        p = atomicAdd(&lcnt[d4.y >> 7], 1u); part[p] = (unsigned)s4.y | ((unsigned)(d4.y & 127) << 20);
        p = atomicAdd(&lcnt[d4.z >> 7], 1u); part[p] = (unsigned)s4.z | ((unsigned)(d4.z & 127) << 20);
        p = atomicAdd(&lcnt[d4.w >> 7], 1u); part[p] = (unsigned)s4.w | ((unsigned)(d4.w & 127) << 20);
    }
}

// P4: one block per bucket. Count per node in LDS, scan, emit rp/dinv, regroup col.
__launch_bounds__(256)
__global__ void p4_csr_k(const unsigned* __restrict__ part, const unsigned* __restrict__ base,
                         unsigned* __restrict__ rp, float* __restrict__ dinv,
                         unsigned* __restrict__ col) {
    __shared__ unsigned c[128], p[128], run[128];
    int tid = threadIdx.x, k = blockIdx.x;
    int n0 = k << 7;
    int nodes = (NN - n0 < 128) ? (NN - n0) : 128;
    unsigned e0 = base[k], e1 = base[k + 1];

    if (tid < 128) c[tid] = 0u;
    __syncthreads();
    for (unsigned e = e0 + tid; e < e1; e += 256)
        atomicAdd(&c[(part[e] >> 20) & 127], 1u);
    __syncthreads();

    unsigned myc = (tid < 128) ? c[tid] : 0u;
    if (tid < 128) p[tid] = myc;
    __syncthreads();
    for (int off = 1; off < 128; off <<= 1) {
        unsigned u = 0;
        if (tid < 128 && tid >= off) u = p[tid - off];
        __syncthreads();
        if (tid < 128) p[tid] += u;
        __syncthreads();
    }
    if (tid < 128) {
        unsigned excl = p[tid] - myc;
        run[tid] = excl;
        if (tid < nodes) {
            rp[n0 + tid] = e0 + excl;
            dinv[n0 + tid] = rsqrtf((float)(myc + 1u));
        }
    }
    if (k == 0 && tid == 0) rp[NN] = NE;
    __syncthreads();

    for (unsigned e = e0 + tid; e < e1; e += 256) {
        unsigned v = part[e];
        unsigned dlo = (v >> 20) & 127;
        unsigned pos = e0 + atomicAdd(&run[dlo], 1u);
        col[pos] = v & 0xFFFFFu;
    }
}

// h' = dinv ⊙ (x @ W1), fp16 out, MFMA 16x16x32 f16. 128 rows/block, 4 waves;
// wave w covers rows w*32..w*32+31 (2 row-tiles) × all 8 col-tiles.
// Verified layouts: A[m=lane&15][k=(lane>>4)*8+j], B[k][n=lane&15],
//                   C/D col=lane&15 row=(lane>>4)*4+reg.
__launch_bounds__(256)
__global__ void gemm1_k(const float* __restrict__ x, const _Float16* __restrict__ Wt,
                        const float* __restrict__ dinv, _Float16* __restrict__ h) {
    __shared__ _Float16 wt[128 * 136];  // B: wt[n][k]; reused as epilogue buffer
    __shared__ _Float16 xs[128 * 72];   // A: xs[row][k within 64-half]
    int tid = threadIdx.x;
    int rb = blockIdx.x * 128;
    int w = tid >> 6, lane = tid & 63;
    int m = lane & 15, q4 = lane >> 4;

#pragma unroll
    for (int q = 0; q < 8; q++) {
        int idx = q * 256 + tid;
        int n = idx >> 4, k8 = (idx & 15) * 8;
        *(half8*)(&wt[n * 136 + k8]) = *(const half8*)(Wt + n * 128 + k8);
    }

    f32x4 acc[2][8];
#pragma unroll
    for (int rt = 0; rt < 2; rt++)
#pragma unroll
        for (int nt = 0; nt < 8; nt++) acc[rt][nt] = (f32x4){0.f, 0.f, 0.f, 0.f};

    for (int ks = 0; ks <= 64; ks += 64) {
        if (ks) __syncthreads();
#pragma unroll
        for (int q = 0; q < 8; q++) {
            int idx = q * 256 + tid;
            int row = idx >> 4;
            int c4 = (idx & 15) * 4;
            int gr = rb + row;
            float4 v = (gr < NN) ? *(const float4*)(x + (size_t)gr * 128 + ks + c4)
                                 : make_float4(0, 0, 0, 0);
            half4v hv = { (_Float16)v.x, (_Float16)v.y, (_Float16)v.z, (_Float16)v.w };
            *(half4v*)(&xs[row * 72 + c4]) = hv;
        }
        __syncthreads();

#pragma unroll
        for (int kc = 0; kc < 2; kc++) {
            half8 a0 = *(const half8*)(&xs[(w * 32 + m) * 72 + kc * 32 + q4 * 8]);
            half8 a1 = *(const half8*)(&xs[(w * 32 + 16 + m) * 72 + kc * 32 + q4 * 8]);
#pragma unroll
            for (int nt = 0; nt < 8; nt++) {
                half8 bf = *(const half8*)(&wt[(nt * 16 + m) * 136 + ks + kc * 32 + q4 * 8]);
                acc[0][nt] = __builtin_amdgcn_mfma_f32_16x16x32_f16(a0, bf, acc[0][nt], 0, 0, 0);
                acc[1][nt] = __builtin_amdgcn_mfma_f32_16x16x32_f16(a1, bf, acc[1][nt], 0, 0, 0);
            }
        }
    }

    float dv[2][4];
#pragma unroll
    for (int rt = 0; rt < 2; rt++)
#pragma unroll
        for (int r = 0; r < 4; r++) {
            int ri = rb + w * 32 + rt * 16 + q4 * 4 + r;
            dv[rt][r] = (ri < NN) ? dinv[ri] : 0.f;
        }
    __syncthreads();
#pragma unroll
    for (int rt = 0; rt < 2; rt++)
#pragma unroll
        for (int nt = 0; nt < 8; nt++)
#pragma unroll
            for (int r = 0; r < 4; r++)
                wt[(w * 32 + rt * 16 + q4 * 4 + r) * 136 + nt * 16 + m] =
                    (_Float16)(acc[rt][nt][r] * dv[rt][r]);
    __syncthreads();
#pragma unroll
    for (int q = 0; q < 8; q++) {
        int idx = q * 256 + tid;
        int row = idx >> 4;
        int c8 = (idx & 15) * 8;
        int gr = rb + row;
        if (gr < NN)
            *(half8*)(h + (size_t)gr * 128 + c8) = *(const half8*)(&wt[row * 136 + c8]);
    }
}

#define GATHER(sv, vv) \
    { unsigned s_ = __builtin_amdgcn_readfirstlane(col[sv]); \
      vv = __half22float2(hb[(size_t)(s_ * 64u + lane)]); }

// Layer-1 aggregation of prescaled h' + bias/ReLU + 128x2 W2 projection.
__launch_bounds__(256)
__global__ void agg1_k(const _Float16* __restrict__ h, const unsigned* __restrict__ rp,
                       const unsigned* __restrict__ col, const float* __restrict__ dinv,
                       const float* __restrict__ b1, const float* __restrict__ W2,
                       float* __restrict__ z) {
    int i = (blockIdx.x * 256 + threadIdx.x) >> 6;
    int lane = threadIdx.x & 63;
    if (i >= NN) return;

    const __half2* hb = (const __half2*)h;
    float di = dinv[i];
    float2 hv = __half22float2(hb[(size_t)i * 64 + lane]);
    float ax = hv.x, ay = hv.y;  // self term h'[i]

    unsigned p0 = __builtin_amdgcn_readfirstlane(rp[i]);
    unsigned p1 = __builtin_amdgcn_readfirstlane(rp[i + 1]);
    unsigned e = p0;
    for (; e + 16 <= p1; e += 16) {
        float2 v0, v1, v2, v3, v4, v5, v6, v7, v8, v9, va, vb, vc, vd, ve, vf;
        GATHER(e, v0)      GATHER(e + 1, v1)  GATHER(e + 2, v2)  GATHER(e + 3, v3)
        GATHER(e + 4, v4)  GATHER(e + 5, v5)  GATHER(e + 6, v6)  GATHER(e + 7, v7)
        GATHER(e + 8, v8)  GATHER(e + 9, v9)  GATHER(e + 10, va) GATHER(e + 11, vb)
        GATHER(e + 12, vc) GATHER(e + 13, vd) GATHER(e + 14, ve) GATHER(e + 15, vf)
        ax += ((v0.x + v1.x) + (v2.x + v3.x)) + ((v4.x + v5.x) + (v6.x + v7.x))
            + ((v8.x + v9.x) + (va.x + vb.x)) + ((vc.x + vd.x) + (ve.x + vf.x));
        ay += ((v0.y + v1.y) + (v2.y + v3.y)) + ((v4.y + v5.y) + (v6.y + v7.y))
            + ((v8.y + v9.y) + (va.y + vb.y)) + ((vc.y + vd.y) + (ve.y + vf.y));
    }
    for (; e + 4 <= p1; e += 4) {
        float2 v0, v1, v2, v3;
        GATHER(e, v0) GATHER(e + 1, v1) GATHER(e + 2, v2) GATHER(e + 3, v3)
        ax += (v0.x + v1.x) + (v2.x + v3.x);
        ay += (v0.y + v1.y) + (v2.y + v3.y);
    }
    for (; e < p1; ++e) {
        float2 v;
        GATHER(e, v)
        ax += v.x;
        ay += v.y;
    }
    ax *= di;
    ay *= di;

    float2 bv = ((const float2*)b1)[lane];
    float h0 = fmaxf(ax + bv.x, 0.f);
    float h1 = fmaxf(ay + bv.y, 0.f);

    float4 w = ((const float4*)W2)[lane];
    float pz0 = fmaf(h0, w.x, h1 * w.z);
    float pz1 = fmaf(h0, w.y, h1 * w.w);
#pragma unroll
    for (int off = 32; off > 0; off >>= 1) {
        pz0 += __shfl_down(pz0, off);
        pz1 += __shfl_down(pz1, off);
    }
    if (lane == 0) {
        float2* zp = (float2*)(z + (size_t)i * 2);
        *zp = make_float2(pz0 * di, pz1 * di);  // prescale for layer-2 aggregation
    }
}

// Layer-2 aggregation over prescaled z'. 16 lanes per node.
__launch_bounds__(256)
__global__ void agg2_k(const float* __restrict__ z, const unsigned* __restrict__ rp,
                       const unsigned* __restrict__ col, const float* __restrict__ dinv,
                       const float* __restrict__ b2, float* __restrict__ out) {
    int i = (blockIdx.x * 256 + threadIdx.x) >> 4;
    int sl = threadIdx.x & 15;
    if (i >= NN) return;

    unsigned p0 = rp[i], p1 = rp[i + 1];
    float a0 = 0.f, a1 = 0.f;
    for (unsigned e = p0 + sl; e < p1; e += 16) {
        unsigned s = col[e];
        float2 v = ((const float2*)z)[s];
        a0 += v.x;
        a1 += v.y;
    }
#pragma unroll
    for (int off = 8; off > 0; off >>= 1) {
        a0 += __shfl_down(a0, off, 16);
        a1 += __shfl_down(a1, off, 16);
    }
    if (sl == 0) {
        float di = dinv[i];
        float2 zi = ((const float2*)z)[i];
        out[(size_t)i * 2]     = (a0 + zi.x) * di + b2[0];
        out[(size_t)i * 2 + 1] = (a1 + zi.y) * di + b2[1];
    }
}

extern "C" void kernel_launch(void* const* d_in, const int* in_sizes, int n_in,
                              void* d_out, int out_size, void* d_ws, size_t ws_size,
                              hipStream_t stream) {
    const float* x  = (const float*)d_in[0];
    const int*   ei = (const int*)d_in[1];
    const float* W1 = (const float*)d_in[2];
    const float* b1 = (const float*)d_in[3];
    const float* W2 = (const float*)d_in[4];
    const float* b2 = (const float*)d_in[5];
    float* out = (float*)d_out;

    char* ws = (char*)d_ws;
    unsigned* part = (unsigned*)(ws);               // overlaps h, dead before gemm1
    unsigned* offs = (unsigned*)(ws + 6400000);     // overlaps h
    unsigned* base = (unsigned*)(ws + 7100000);     // overlaps h
    _Float16* h    = (_Float16*)(ws);
    float*    z    = (float*)(ws + 25600000);
    float*    dinv = (float*)(ws + 26400000);
    unsigned* rp   = (unsigned*)(ws + 26800000);
    unsigned* col  = (unsigned*)(ws + 27200016);
    _Float16* Wt   = (_Float16*)(ws + 33600016);

    p1_count_k<<<NBLK_P, 1024, 0, stream>>>(ei, offs, W1, Wt);
    p2a_k<<<NBK, 256, 0, stream>>>(offs, base);
    p2b_k<<<1, 1024, 0, stream>>>(base);
    p3_scatter_k<<<NBLK_P, 1024, 0, stream>>>(ei, offs, base, part);
    p4_csr_k<<<NBK, 256, 0, stream>>>(part, base, rp, dinv, col);

    gemm1_k<<<(NN + 127) / 128, 256, 0, stream>>>(x, Wt, dinv, h);
    agg1_k<<<(NN + 3) / 4, 256, 0, stream>>>(h, rp, col, dinv, b1, W2, z);
    agg2_k<<<(NN * 16 + 255) / 256, 256, 0, stream>>>(z, rp, col, dinv, b2, out);
}

// Round 14
// 225.362 us; speedup vs baseline: 2.9315x; 1.0006x over previous
//
#include <hip/hip_runtime.h>
#include <hip/hip_fp16.h>
#include <cstdint>
#include <cstddef>

#define NN 100000
#define NE 1600000
#define D 128
#define NBK 782            // ceil(NN / 128) buckets of 128 nodes
#define NBLK_P 200         // partition chunks
#define EPB 8000           // edges per chunk (200*8000 = 1.6M exact)
#define BPB 16             // buckets per p2a block

typedef _Float16 half8 __attribute__((ext_vector_type(8)));
typedef _Float16 half4v __attribute__((ext_vector_type(4)));
typedef float f32x4 __attribute__((ext_vector_type(4)));

// ---------------- workspace layout (bytes) ----------------
// part  : NE u32      @ 0          (6,400,000)   } dead after p4_csr; overlapped by h
// offs  : 200*782 u32 @ 6,400,000  (  625,600)   }
// base  : 783 u32     @ 7,100,000  (    3,132)   }
// h'    : NN*128 f16  @ 0          (25,600,000)  = dinv[row] * (x@W1), written after CSR
// z'    : NN*2 f32    @ 25,600,000 (   800,000)
// dinv  : NN f32      @ 26,400,000 (   400,000)
// rp    : NN+1 u32    @ 26,800,000 (   400,004)
// col   : NE u32      @ 27,200,016 ( 6,400,000)
// Wt    : 128*128 f16 @ 33,600,016 (    32,768)  -> total 33,632,784

// P1: per-chunk LDS histogram over dst buckets. Blocks 0..15 also emit
// Wt[n][k] = fp16 W1[k][n].
__launch_bounds__(1024)
__global__ void p1_count_k(const int* __restrict__ ei, unsigned* __restrict__ offs,
                           const float* __restrict__ W, _Float16* __restrict__ Wt) {
    __shared__ unsigned hist[NBK];
    int tid = threadIdx.x, b = blockIdx.x;
    for (int k = tid; k < NBK; k += 1024) hist[k] = 0u;
    __syncthreads();
    int e0 = b * EPB;
    for (int i = tid * 4; i < EPB; i += 4096) {
        int4 d4 = *(const int4*)(ei + NE + e0 + i);
        atomicAdd(&hist[d4.x >> 7], 1u);
        atomicAdd(&hist[d4.y >> 7], 1u);
        atomicAdd(&hist[d4.z >> 7], 1u);
        atomicAdd(&hist[d4.w >> 7], 1u);
    }
    if (b < 16) {  // fused Wt transpose+cast (16384 elems over 16 blocks)
        int idx = b * 1024 + tid;
        int n = idx >> 7, k = idx & 127;
        Wt[idx] = (_Float16)W[k * 128 + n];
    }
    __syncthreads();
    for (int k = tid; k < NBK; k += 1024) offs[(size_t)b * NBK + k] = hist[k];
}

// P2a: 16 buckets per block, coalesced 64B-run loads (was: 200 strided lines
// per bucket = 10 MB line traffic). Scan per bucket: 16 lanes x 13-chunk
// serial segments + width-16 shfl exclusive combine; 2 barriers total.
__launch_bounds__(256)
__global__ void p2a_k(unsigned* __restrict__ offs, unsigned* __restrict__ base) {
    __shared__ unsigned tile[NBLK_P][BPB + 1];
    int tid = threadIdx.x;
    int k0 = blockIdx.x * BPB;

    for (int idx = tid; idx < NBLK_P * BPB; idx += 256) {
        int b = idx >> 4, kk = idx & 15;
        int k = k0 + kk;
        tile[b][kk] = (k < NBK) ? offs[(size_t)b * NBK + k] : 0u;
    }
    __syncthreads();

    {
        int g = tid >> 4;      // bucket-local index 0..15
        int l = tid & 15;      // lane within bucket group
        // serial exclusive scan over this lane's 13-chunk segment
        unsigned s = 0;
        #pragma unroll
        for (int j = 0; j < 13; j++) {
            int b = l * 13 + j;
            if (b < NBLK_P) {
                unsigned u = tile[b][g];
                tile[b][g] = s;
                s += u;
            }
        }
        // width-16 exclusive scan of segment totals
        unsigned incl = s;
        #pragma unroll
        for (int off = 1; off < 16; off <<= 1) {
            unsigned u = __shfl_up(incl, off, 16);
            if (l >= off) incl += u;
        }
        unsigned excl = incl - s;
        unsigned total = __shfl(incl, 15, 16);
        #pragma unroll
        for (int j = 0; j < 13; j++) {
            int b = l * 13 + j;
            if (b < NBLK_P) tile[b][g] += excl;
        }
        if (l == 0 && k0 + g < NBK) base[k0 + g] = total;
    }
    __syncthreads();

    for (int idx = tid; idx < NBLK_P * BPB; idx += 256) {
        int b = idx >> 4, kk = idx & 15;
        int k = k0 + kk;
        if (k < NBK) offs[(size_t)b * NBK + k] = tile[b][kk];
    }
}

// P2b: exclusive scan of bucket totals; base[NBK] = NE.
__global__ void p2b_k(unsigned* __restrict__ base) {
    __shared__ unsigned sh[1024];
    int t = threadIdx.x;
    unsigned v = (t < NBK) ? base[t] : 0u;
    sh[t] = v;
    __syncthreads();
    for (int off = 1; off < 1024; off <<= 1) {
        unsigned u = (t >= off) ? sh[t - off] : 0u;
        __syncthreads();
        sh[t] += u;
        __syncthreads();
    }
    if (t < NBK) base[t] = sh[t] - v;
    if (t == NBK) base[NBK] = sh[NBK - 1];
}

// P3: scatter packed edges into bucket-partitioned order via LDS running counters.
__launch_bounds__(1024)
__global__ void p3_scatter_k(const int* __restrict__ ei, const unsigned* __restrict__ offs,
                             const unsigned* __restrict__ base, unsigned* __restrict__ part) {
    __shared__ unsigned lcnt[NBK];
    int tid = threadIdx.x, b = blockIdx.x;
    for (int k = tid; k < NBK; k += 1024) lcnt[k] = base[k] + offs[(size_t)b * NBK + k];
    __syncthreads();
    int e0 = b * EPB;
    for (int i = tid * 4; i < EPB; i += 4096) {
        int4 s4 = *(const int4*)(ei + e0 + i);
        int4 d4 = *(const int4*)(ei + NE + e0 + i);
        unsigned p;
        p = atomicAdd(&lcnt[d4.x >> 7], 1u); part[p] = (unsigned)s4.x | ((unsigned)(d4.x & 127) << 20);
        p = atomicAdd(&lcnt[d4.y >> 7], 1u); part[p] = (unsigned)s4.y | ((unsigned)(d4.y & 127) << 20);
        p = atomicAdd(&lcnt[d4.z >> 7], 1u); part[p] = (unsigned)s4.z | ((unsigned)(d4.z & 127) << 20);
        p = atomicAdd(&lcnt[d4.w >> 7], 1u); part[p] = (unsigned)s4.w | ((unsigned)(d4.w & 127) << 20);
    }
}

// P4: one block per bucket (512 thr). Count per node in LDS, scan, emit
// rp/dinv, regroup col.
__launch_bounds__(512)
__global__ void p4_csr_k(const unsigned* __restrict__ part, const unsigned* __restrict__ base,
                         unsigned* __restrict__ rp, float* __restrict__ dinv,
                         unsigned* __restrict__ col) {
    __shared__ unsigned c[128], p[128], run[128];
    int tid = threadIdx.x, k = blockIdx.x;
    int n0 = k << 7;
    int nodes = (NN - n0 < 128) ? (NN - n0) : 128;
    unsigned e0 = base[k], e1 = base[k + 1];

    if (tid < 128) c[tid] = 0u;
    __syncthreads();
    for (unsigned e = e0 + tid; e < e1; e += 512)
        atomicAdd(&c[(part[e] >> 20) & 127], 1u);
    __syncthreads();

    unsigned myc = (tid < 128) ? c[tid] : 0u;
    if (tid < 128) p[tid] = myc;
    __syncthreads();
    for (int off = 1; off < 128; off <<= 1) {
        unsigned u = 0;
        if (tid < 128 && tid >= off) u = p[tid - off];
        __syncthreads();
        if (tid < 128) p[tid] += u;
        __syncthreads();
    }
    if (tid < 128) {
        unsigned excl = p[tid] - myc;
        run[tid] = excl;
        if (tid < nodes) {
            rp[n0 + tid] = e0 + excl;
            dinv[n0 + tid] = rsqrtf((float)(myc + 1u));
        }
    }
    if (k == 0 && tid == 0) rp[NN] = NE;
    __syncthreads();

    for (unsigned e = e0 + tid; e < e1; e += 512) {
        unsigned v = part[e];
        unsigned dlo = (v >> 20) & 127;
        unsigned pos = e0 + atomicAdd(&run[dlo], 1u);
        col[pos] = v & 0xFFFFFu;
    }
}

// h' = dinv ⊙ (x @ W1), fp16 out, MFMA 16x16x32 f16. 128 rows/block, 4 waves.
// Verified layouts: A[m=lane&15][k=(lane>>4)*8+j], B[k][n=lane&15],
//                   C/D col=lane&15 row=(lane>>4)*4+reg.
__launch_bounds__(256)
__global__ void gemm1_k(const float* __restrict__ x, const _Float16* __restrict__ Wt,
                        const float* __restrict__ dinv, _Float16* __restrict__ h) {
    __shared__ _Float16 wt[128 * 136];  // B: wt[n][k]; reused as epilogue buffer
    __shared__ _Float16 xs[128 * 72];   // A: xs[row][k within 64-half]
    int tid = threadIdx.x;
    int rb = blockIdx.x * 128;
    int w = tid >> 6, lane = tid & 63;
    int m = lane & 15, q4 = lane >> 4;

#pragma unroll
    for (int q = 0; q < 8; q++) {
        int idx = q * 256 + tid;
        int n = idx >> 4, k8 = (idx & 15) * 8;
        *(half8*)(&wt[n * 136 + k8]) = *(const half8*)(Wt + n * 128 + k8);
    }

    f32x4 acc[2][8];
#pragma unroll
    for (int rt = 0; rt < 2; rt++)
#pragma unroll
        for (int nt = 0; nt < 8; nt++) acc[rt][nt] = (f32x4){0.f, 0.f, 0.f, 0.f};

    for (int ks = 0; ks <= 64; ks += 64) {
        if (ks) __syncthreads();
#pragma unroll
        for (int q = 0; q < 8; q++) {
            int idx = q * 256 + tid;
            int row = idx >> 4;
            int c4 = (idx & 15) * 4;
            int gr = rb + row;
            float4 v = (gr < NN) ? *(const float4*)(x + (size_t)gr * 128 + ks + c4)
                                 : make_float4(0, 0, 0, 0);
            half4v hv = { (_Float16)v.x, (_Float16)v.y, (_Float16)v.z, (_Float16)v.w };
            *(half4v*)(&xs[row * 72 + c4]) = hv;
        }
        __syncthreads();

#pragma unroll
        for (int kc = 0; kc < 2; kc++) {
            half8 a0 = *(const half8*)(&xs[(w * 32 + m) * 72 + kc * 32 + q4 * 8]);
            half8 a1 = *(const half8*)(&xs[(w * 32 + 16 + m) * 72 + kc * 32 + q4 * 8]);
#pragma unroll
            for (int nt = 0; nt < 8; nt++) {
                half8 bf = *(const half8*)(&wt[(nt * 16 + m) * 136 + ks + kc * 32 + q4 * 8]);
                acc[0][nt] = __builtin_amdgcn_mfma_f32_16x16x32_f16(a0, bf, acc[0][nt], 0, 0, 0);
                acc[1][nt] = __builtin_amdgcn_mfma_f32_16x16x32_f16(a1, bf, acc[1][nt], 0, 0, 0);
            }
        }
    }

    float dv[2][4];
#pragma unroll
    for (int rt = 0; rt < 2; rt++)
#pragma unroll
        for (int r = 0; r < 4; r++) {
            int ri = rb + w * 32 + rt * 16 + q4 * 4 + r;
            dv[rt][r] = (ri < NN) ? dinv[ri] : 0.f;
        }
    __syncthreads();
#pragma unroll
    for (int rt = 0; rt < 2; rt++)
#pragma unroll
        for (int nt = 0; nt < 8; nt++)
#pragma unroll
            for (int r = 0; r < 4; r++)
                wt[(w * 32 + rt * 16 + q4 * 4 + r) * 136 + nt * 16 + m] =
                    (_Float16)(acc[rt][nt][r] * dv[rt][r]);
    __syncthreads();
#pragma unroll
    for (int q = 0; q < 8; q++) {
        int idx = q * 256 + tid;
        int row = idx >> 4;
        int c8 = (idx & 15) * 8;
        int gr = rb + row;
        if (gr < NN)
            *(half8*)(h + (size_t)gr * 128 + c8) = *(const half8*)(&wt[row * 136 + c8]);
    }
}

#define GATHER(sv, vv) \
    { unsigned s_ = __builtin_amdgcn_readfirstlane(col[sv]); \
      vv = __half22float2(hb[(size_t)(s_ * 64u + lane)]); }

// Layer-1 aggregation of prescaled h' + bias/ReLU + 128x2 W2 projection.
__launch_bounds__(256)
__global__ void agg1_k(const _Float16* __restrict__ h, const unsigned* __restrict__ rp,
                       const unsigned* __restrict__ col, const float* __restrict__ dinv,
                       const float* __restrict__ b1, const float* __restrict__ W2,
                       float* __restrict__ z) {
    int i = (blockIdx.x * 256 + threadIdx.x) >> 6;
    int lane = threadIdx.x & 63;
    if (i >= NN) return;

    const __half2* hb = (const __half2*)h;
    float di = dinv[i];
    float2 hv = __half22float2(hb[(size_t)i * 64 + lane]);
    float ax = hv.x, ay = hv.y;  // self term h'[i]

    unsigned p0 = __builtin_amdgcn_readfirstlane(rp[i]);
    unsigned p1 = __builtin_amdgcn_readfirstlane(rp[i + 1]);
    unsigned e = p0;
    for (; e + 16 <= p1; e += 16) {
        float2 v0, v1, v2, v3, v4, v5, v6, v7, v8, v9, va, vb, vc, vd, ve, vf;
        GATHER(e, v0)      GATHER(e + 1, v1)  GATHER(e + 2, v2)  GATHER(e + 3, v3)
        GATHER(e + 4, v4)  GATHER(e + 5, v5)  GATHER(e + 6, v6)  GATHER(e + 7, v7)
        GATHER(e + 8, v8)  GATHER(e + 9, v9)  GATHER(e + 10, va) GATHER(e + 11, vb)
        GATHER(e + 12, vc) GATHER(e + 13, vd) GATHER(e + 14, ve) GATHER(e + 15, vf)
        ax += ((v0.x + v1.x) + (v2.x + v3.x)) + ((v4.x + v5.x) + (v6.x + v7.x))
            + ((v8.x + v9.x) + (va.x + vb.x)) + ((vc.x + vd.x) + (ve.x + vf.x));
        ay += ((v0.y + v1.y) + (v2.y + v3.y)) + ((v4.y + v5.y) + (v6.y + v7.y))
            + ((v8.y + v9.y) + (va.y + vb.y)) + ((vc.y + vd.y) + (ve.y + vf.y));
    }
    for (; e + 4 <= p1; e += 4) {
        float2 v0, v1, v2, v3;
        GATHER(e, v0) GATHER(e + 1, v1) GATHER(e + 2, v2) GATHER(e + 3, v3)
        ax += (v0.x + v1.x) + (v2.x + v3.x);
        ay += (v0.y + v1.y) + (v2.y + v3.y);
    }
    for (; e < p1; ++e) {
        float2 v;
        GATHER(e, v)
        ax += v.x;
        ay += v.y;
    }
    ax *= di;
    ay *= di;

    float2 bv = ((const float2*)b1)[lane];
    float h0 = fmaxf(ax + bv.x, 0.f);
    float h1 = fmaxf(ay + bv.y, 0.f);

    float4 w = ((const float4*)W2)[lane];
    float pz0 = fmaf(h0, w.x, h1 * w.z);
    float pz1 = fmaf(h0, w.y, h1 * w.w);
#pragma unroll
    for (int off = 32; off > 0; off >>= 1) {
        pz0 += __shfl_down(pz0, off);
        pz1 += __shfl_down(pz1, off);
    }
    if (lane == 0) {
        float2* zp = (float2*)(z + (size_t)i * 2);
        *zp = make_float2(pz0 * di, pz1 * di);  // prescale for layer-2 aggregation
    }
}

// Layer-2 aggregation over prescaled z'. 16 lanes per node.
__launch_bounds__(256)
__global__ void agg2_k(const float* __restrict__ z, const unsigned* __restrict__ rp,
                       const unsigned* __restrict__ col, const float* __restrict__ dinv,
                       const float* __restrict__ b2, float* __restrict__ out) {
    int i = (blockIdx.x * 256 + threadIdx.x) >> 4;
    int sl = threadIdx.x & 15;
    if (i >= NN) return;

    unsigned p0 = rp[i], p1 = rp[i + 1];
    float a0 = 0.f, a1 = 0.f;
    for (unsigned e = p0 + sl; e < p1; e += 16) {
        unsigned s = col[e];
        float2 v = ((const float2*)z)[s];
        a0 += v.x;
        a1 += v.y;
    }
#pragma unroll
    for (int off = 8; off > 0; off >>= 1) {
        a0 += __shfl_down(a0, off, 16);
        a1 += __shfl_down(a1, off, 16);
    }
    if (sl == 0) {
        float di = dinv[i];
        float2 zi = ((const float2*)z)[i];
        out[(size_t)i * 2]     = (a0 + zi.x) * di + b2[0];
        out[(size_t)i * 2 + 1] = (a1 + zi.y) * di + b2[1];
    }
}

extern "C" void kernel_launch(void* const* d_in, const int* in_sizes, int n_in,
                              void* d_out, int out_size, void* d_ws, size_t ws_size,
                              hipStream_t stream) {
    const float* x  = (const float*)d_in[0];
    const int*   ei = (const int*)d_in[1];
    const float* W1 = (const float*)d_in[2];
    const float* b1 = (const float*)d_in[3];
    const float* W2 = (const float*)d_in[4];
    const float* b2 = (const float*)d_in[5];
    float* out = (float*)d_out;

    char* ws = (char*)d_ws;
    unsigned* part = (unsigned*)(ws);               // overlaps h, dead before gemm1
    unsigned* offs = (unsigned*)(ws + 6400000);     // overlaps h
    unsigned* base = (unsigned*)(ws + 7100000);     // overlaps h
    _Float16* h    = (_Float16*)(ws);
    float*    z    = (float*)(ws + 25600000);
    float*    dinv = (float*)(ws + 26400000);
    unsigned* rp   = (unsigned*)(ws + 26800000);
    unsigned* col  = (unsigned*)(ws + 27200016);
    _Float16* Wt   = (_Float16*)(ws + 33600016);

    p1_count_k<<<NBLK_P, 1024, 0, stream>>>(ei, offs, W1, Wt);
    p2a_k<<<(NBK + BPB - 1) / BPB, 256, 0, stream>>>(offs, base);
    p2b_k<<<1, 1024, 0, stream>>>(base);
    p3_scatter_k<<<NBLK_P, 1024, 0, stream>>>(ei, offs, base, part);
    p4_csr_k<<<NBK, 512, 0, stream>>>(part, base, rp, dinv, col);

    gemm1_k<<<(NN + 127) / 128, 256, 0, stream>>>(x, Wt, dinv, h);
    agg1_k<<<(NN + 3) / 4, 256, 0, stream>>>(h, rp, col, dinv, b1, W2, z);
    agg2_k<<<(NN * 16 + 255) / 256, 256, 0, stream>>>(z, rp, col, dinv, b2, out);
}